// Round 8
// baseline (227.132 us; speedup 1.0000x reference)
//
#include <hip/hip_runtime.h>
#include <math.h>

// R7 ABLATION (resubmit after GPU-acquisition timeout): is the ~50us read wall
// the one-shot burst shape (H1) or the read path itself (H2)?
//   probe_stream: sustained grid-stride streaming reduction (compiler pipelines
//     loads with partial vmcnt) — the m146-RMSNorm-proven shape.
//   probe_nt:     same with nontemporal loads (read-once data, skip cache alloc).
//   ndcg_main_kernel: R5 verbatim (correct, absmax 0.0) for the score.

#define G 128

typedef float f4v __attribute__((ext_vector_type(4)));
typedef int   i4v __attribute__((ext_vector_type(4)));

// ws float layout: [0..127] disc, [128..256] cumdisc, [512..2559] partials,
//                  [4096..] probe sink
__global__ void build_tables_kernel(float* __restrict__ tabs) {
    int t = threadIdx.x;
    if (t < G) {
        tabs[t] = 1.0f / log2f((float)(t + 2));
    }
    if (t <= G) {
        float s = 0.0f;
        for (int p = 1; p <= t; ++p) s += 1.0f / log2f((float)(p + 1));
        tabs[G + t] = s;
    }
}

__global__ __launch_bounds__(256) void probe_stream(
        const float* __restrict__ scores,
        const int*   __restrict__ labels,
        float*       __restrict__ sink,
        int n4) {
    const f4v* s4 = (const f4v*)scores;
    const i4v* l4 = (const i4v*)labels;
    const int tid    = blockIdx.x * 256 + threadIdx.x;
    const int stride = gridDim.x * 256;
    float a = 0.0f;
    int   c = 0;
    for (int i = tid; i < n4; i += stride) {
        const f4v x = s4[i];
        const i4v y = l4[i];
        a += (x[0] + x[1]) + (x[2] + x[3]);
        c += (y[0] + y[1]) + (y[2] + y[3]);
    }
    sink[tid] = a + (float)c;
}

__global__ __launch_bounds__(256) void probe_nt(
        const float* __restrict__ scores,
        const int*   __restrict__ labels,
        float*       __restrict__ sink,
        int n4) {
    const f4v* s4 = (const f4v*)scores;
    const i4v* l4 = (const i4v*)labels;
    const int tid    = blockIdx.x * 256 + threadIdx.x;
    const int stride = gridDim.x * 256;
    float a = 0.0f;
    int   c = 0;
    for (int i = tid; i < n4; i += stride) {
        const f4v x = __builtin_nontemporal_load(&s4[i]);
        const i4v y = __builtin_nontemporal_load(&l4[i]);
        a += (x[0] + x[1]) + (x[2] + x[3]);
        c += (y[0] + y[1]) + (y[2] + y[3]);
    }
    sink[tid] = a + (float)c;
}

// ===== R5 main kernel, verbatim (absmax 0.0) =====
__global__ __launch_bounds__(256, 4) void ndcg_main_kernel(
        const float* __restrict__ scores,
        const int*   __restrict__ labels,
        const float* __restrict__ tabs,
        float*       __restrict__ partials,
        int B) {
    const int t    = threadIdx.x;
    const int lane = t & 63;
    const int li   = lane & 15;
    const int gs   = lane >> 4;
    const int wib  = t >> 6;
    const long long wave  = (long long)blockIdx.x * 4 + wib;
    const long long gbase = wave * 16;

    __shared__ float bsum;
    if (t == 0) bsum = 0.0f;
    __syncthreads();

    if (gbase < B) {
        const float4* dv = (const float4*)tabs;
        const float4 dA = dv[li];
        const float4 dB = dv[16 + li];

        float4 sA[4], sB[4];
        int4   lA[4], lB[4];
#pragma unroll
        for (int q = 0; q < 4; ++q) {
            const long long g = gbase + q * 4 + gs;
            const float4* sp = (const float4*)(scores + g * G);
            const int4*   lp = (const int4*)(labels + g * G);
            sA[q] = sp[li];
            sB[q] = sp[16 + li];
            lA[q] = lp[li];
            lB[q] = lp[16 + li];
        }

        float esum[4], num[4], cntf[4];
#pragma unroll
        for (int q = 0; q < 4; ++q) {
            float e0 = __expf(sA[q].x), e1 = __expf(sA[q].y);
            float e2 = __expf(sA[q].z), e3 = __expf(sA[q].w);
            float e4 = __expf(sB[q].x), e5 = __expf(sB[q].y);
            float e6 = __expf(sB[q].z), e7 = __expf(sB[q].w);
            esum[q] = ((e0 + e1) + (e2 + e3)) + ((e4 + e5) + (e6 + e7));
            num[q]  = ((e0 * (lA[q].x ? dA.x : 0.f) + e1 * (lA[q].y ? dA.y : 0.f))
                     + (e2 * (lA[q].z ? dA.z : 0.f) + e3 * (lA[q].w ? dA.w : 0.f)))
                    + ((e4 * (lB[q].x ? dB.x : 0.f) + e5 * (lB[q].y ? dB.y : 0.f))
                     + (e6 * (lB[q].z ? dB.z : 0.f) + e7 * (lB[q].w ? dB.w : 0.f)));
            cntf[q] = (float)((lA[q].x + lA[q].y + lA[q].z + lA[q].w)
                            + (lB[q].x + lB[q].y + lB[q].z + lB[q].w));
        }

#pragma unroll
        for (int m = 1; m <= 8; m <<= 1) {
#pragma unroll
            for (int q = 0; q < 4; ++q) {
                esum[q] += __shfl_xor(esum[q], m, 64);
                num[q]  += __shfl_xor(num[q],  m, 64);
                cntf[q] += __shfl_xor(cntf[q], m, 64);
            }
        }

        if (li == 0) {
            float acc = 0.0f;
#pragma unroll
            for (int q = 0; q < 4; ++q) {
                const int c = (int)cntf[q];
                const float idcg = tabs[G + c];
                acc += (c > 0) ? (1.0f - num[q] / (esum[q] * idcg)) : 0.0f;
            }
            atomicAdd(&bsum, acc);
        }
    }
    __syncthreads();
    if (t == 0) partials[blockIdx.x] = bsum;
}

__global__ void finalize_kernel(const float* __restrict__ partials, int n,
                                float* __restrict__ out, float invB) {
    __shared__ float red[256];
    float a = 0.0f;
    for (int i = threadIdx.x; i < n; i += 256) a += partials[i];
    red[threadIdx.x] = a;
    __syncthreads();
    for (int s = 128; s > 0; s >>= 1) {
        if (threadIdx.x < s) red[threadIdx.x] += red[threadIdx.x + s];
        __syncthreads();
    }
    if (threadIdx.x == 0) out[0] = red[0] * invB;
}

extern "C" void kernel_launch(void* const* d_in, const int* in_sizes, int n_in,
                              void* d_out, int out_size, void* d_ws, size_t ws_size,
                              hipStream_t stream) {
    const float* scores = (const float*)d_in[0];
    const int*   labels = (const int*)d_in[1];

    const int n  = in_sizes[0];       // B * G
    const int B  = n / G;             // 131072
    const int n4 = n / 4;             // float4 count = 4194304
    const int NB = (B + 15) / 16 / 4; // 2048

    float* tabs     = (float*)d_ws;
    float* partials = tabs + 512;
    float* sink     = tabs + 4096;    // 1024*256 floats reused by both probes

    // Probes first (post-restore input state), then the scored pipeline.
    probe_stream<<<1024, 256, 0, stream>>>(scores, labels, sink, n4);
    probe_nt<<<1024, 256, 0, stream>>>(scores, labels, sink, n4);
    build_tables_kernel<<<1, 256, 0, stream>>>(tabs);
    ndcg_main_kernel<<<NB, 256, 0, stream>>>(scores, labels, tabs, partials, B);
    finalize_kernel<<<1, 256, 0, stream>>>(partials, NB, (float*)d_out,
                                           1.0f / (float)B);
}

// Round 9
// 175.314 us; speedup vs baseline: 1.2956x; 1.2956x over previous
//
#include <hip/hip_runtime.h>
#include <math.h>

// ApproxNDCGLoss: B=131072 graphs of G=128, fp32 scores, {0,1} int labels.
// loss_g = 1 - (sum_i softmax(s)_i*l_i*disc_i) / cumdisc(sum l_i); out = mean/B.
//
// R9: two-kernel pipeline. Main is the R2 one-shot structure (fastest correct:
// 49.6us) made self-contained: cumdisc built per-block in LDS (prefix scan)
// UNDER the shadow of the in-flight input loads, disc computed inline per lane
// (8 log2f, hidden under vmcnt wait). Inputs read with nontemporal loads
// (read-once data) to probe whether L3-allocation is part of the cold-read tax.
// Evidence so far (R6/R8 ablations): time == pure-load time; ~27us first-
// toucher penalty + ~5.9 TB/s marginal rate, structure-invariant.

#define G 128

typedef float f4v __attribute__((ext_vector_type(4)));
typedef int   i4v __attribute__((ext_vector_type(4)));

// 16 lanes per graph, 8 elements/lane, 4 graphs per wave, one shot per wave.
__global__ __launch_bounds__(256) void ndcg_main_kernel(
        const float* __restrict__ scores,
        const int*   __restrict__ labels,
        float*       __restrict__ partials) {
    const int t    = threadIdx.x;
    const int lane = t & 63;
    const int li   = lane & 15;               // lane within 16-lane graph group
    const int wib  = t >> 6;                  // wave in block
    const long long g    = (long long)blockIdx.x * 16 + wib * 4 + (lane >> 4);
    const long long base = g * G + li * 8;

    // (1) Issue all 4 input loads immediately (nontemporal: read-once data).
    const f4v* sp = (const f4v*)(scores + base);
    const i4v* lp = (const i4v*)(labels + base);
    const f4v sA = __builtin_nontemporal_load(sp);
    const f4v sB = __builtin_nontemporal_load(sp + 1);
    const i4v lA = __builtin_nontemporal_load(lp);
    const i4v lB = __builtin_nontemporal_load(lp + 1);

    // (2) Build cumdisc[0..128] in LDS while the loads are in flight.
    //     cumdisc[c] = sum_{p=1..c} 1/log2(p+1); Hillis-Steele inclusive scan.
    __shared__ float cum[G + 1];
    {
        if (t <= G) cum[t] = (t == 0) ? 0.0f : 1.0f / log2f((float)(t + 1));
        __syncthreads();
#pragma unroll
        for (int off = 1; off <= G; off <<= 1) {
            float u = 0.0f;
            if (t <= G && t >= off) u = cum[t - off];
            __syncthreads();
            if (t <= G) cum[t] += u;
            __syncthreads();
        }
    }

    // (3) Per-lane discount factors, computed inline (hidden under vmcnt wait).
    float d[8];
#pragma unroll
    for (int j = 0; j < 8; ++j) {
        d[j] = 1.0f / log2f((float)(li * 8 + j + 2));   // 1/log2(pos+1), 1-based
    }

    // (4) Consume. Scores ~N(0,1): exp safe in fp32 without max-subtraction
    //     (bit-validated absmax 0.0 in R1/R2/R5/R6).
    const float s[8] = {sA[0], sA[1], sA[2], sA[3], sB[0], sB[1], sB[2], sB[3]};
    const int   l[8] = {lA[0], lA[1], lA[2], lA[3], lB[0], lB[1], lB[2], lB[3]};

    float esum = 0.0f, num = 0.0f;
    int cnt = 0;
#pragma unroll
    for (int j = 0; j < 8; ++j) {
        const float e = __expf(s[j]);
        esum += e;
        num  += e * (l[j] ? d[j] : 0.0f);
        cnt  += l[j];
    }

    float cntf = (float)cnt;
#pragma unroll
    for (int m = 1; m <= 8; m <<= 1) {
        esum += __shfl_xor(esum, m, 64);
        num  += __shfl_xor(num,  m, 64);
        cntf += __shfl_xor(cntf, m, 64);
    }
    const int c = (int)cntf;                  // exact: 0..128
    const float idcg = cum[c];                // LDS gather
    float loss = (c > 0) ? (1.0f - num / (esum * idcg)) : 0.0f;

    // Sum the 4 graph losses across the wave, then 4 waves across the block.
    loss += __shfl_xor(loss, 16, 64);
    loss += __shfl_xor(loss, 32, 64);

    __shared__ float wsum[4];
    if (lane == 0) wsum[wib] = loss;
    __syncthreads();
    if (t == 0)
        partials[blockIdx.x] = (wsum[0] + wsum[1]) + (wsum[2] + wsum[3]);
}

__global__ __launch_bounds__(256) void finalize_kernel(
        const float* __restrict__ partials, int n,
        float* __restrict__ out, float invB) {
    __shared__ float red[256];
    float a = 0.0f;
    for (int i = threadIdx.x; i < n; i += 256) a += partials[i];
    red[threadIdx.x] = a;
    __syncthreads();
    for (int s = 128; s > 0; s >>= 1) {
        if (threadIdx.x < s) red[threadIdx.x] += red[threadIdx.x + s];
        __syncthreads();
    }
    if (threadIdx.x == 0) out[0] = red[0] * invB;
}

extern "C" void kernel_launch(void* const* d_in, const int* in_sizes, int n_in,
                              void* d_out, int out_size, void* d_ws, size_t ws_size,
                              hipStream_t stream) {
    const float* scores = (const float*)d_in[0];
    const int*   labels = (const int*)d_in[1];
    // d_in[2] (batch) encodes contiguous equal-size segments -> not needed.

    const int n  = in_sizes[0];       // B * G
    const int B  = n / G;             // 131072
    const int NB = B / 16;            // 16 graphs per 256-thread block -> 8192

    float* partials = (float*)d_ws;   // [NB]

    ndcg_main_kernel<<<NB, 256, 0, stream>>>(scores, labels, partials);
    finalize_kernel<<<1, 256, 0, stream>>>(partials, NB, (float*)d_out,
                                           1.0f / (float)B);
}